// Round 2
// baseline (594.505 us; speedup 1.0000x reference)
//
#include <hip/hip_runtime.h>
#include <cmath>

#define NPTS 262144
#define NLVL 16
#define TBL  524288u
#define TMASK 524287u

struct ResArr { float r[NLVL]; };

// ---------------------------------------------------------------------------
// Kernel 1: hash-grid encode. One thread per (point, level).
// grid = (NPTS/256, NLVL). Writes feat SoA: float2 ws[level][point].
// ---------------------------------------------------------------------------
__global__ __launch_bounds__(256) void hash_encode_k(
    const float* __restrict__ coords,
    const float* __restrict__ emb,
    float2* __restrict__ featws,
    ResArr res)
{
    const int i = blockIdx.x * 256 + threadIdx.x;
    const int l = blockIdx.y;

    const float cx = coords[3*i+0], cy = coords[3*i+1], cz = coords[3*i+2];
    const float r = res.r[l];

    const float px = cx*r, py = cy*r, pz = cz*r;
    const float fpx = floorf(px), fpy = floorf(py), fpz = floorf(pz);
    const float fx = px - fpx, fy = py - fpy, fz = pz - fpz;
    const unsigned ix = (unsigned)fpx, iy = (unsigned)fpy, iz = (unsigned)fpz;
    const unsigned hx0 = ix,               hx1 = ix + 1u;
    const unsigned hy0 = iy * 2654435761u, hy1 = (iy+1u) * 2654435761u;
    const unsigned hz0 = iz * 805459861u,  hz1 = (iz+1u) * 805459861u;
    const unsigned base = (unsigned)l * TBL;

    const float2* __restrict__ emb2 = reinterpret_cast<const float2*>(emb);
    const float2 f000 = emb2[base + ((hx0^hy0^hz0) & TMASK)];
    const float2 f001 = emb2[base + ((hx0^hy0^hz1) & TMASK)];
    const float2 f010 = emb2[base + ((hx0^hy1^hz0) & TMASK)];
    const float2 f011 = emb2[base + ((hx0^hy1^hz1) & TMASK)];
    const float2 f100 = emb2[base + ((hx1^hy0^hz0) & TMASK)];
    const float2 f101 = emb2[base + ((hx1^hy0^hz1) & TMASK)];
    const float2 f110 = emb2[base + ((hx1^hy1^hz0) & TMASK)];
    const float2 f111 = emb2[base + ((hx1^hy1^hz1) & TMASK)];

    const float wx0 = 1.f-fx, wx1 = fx;
    const float wy0 = 1.f-fy, wy1 = fy;
    const float wz0 = 1.f-fz, wz1 = fz;
    const float w000 = wx0*wy0*wz0, w001 = wx0*wy0*wz1;
    const float w010 = wx0*wy1*wz0, w011 = wx0*wy1*wz1;
    const float w100 = wx1*wy0*wz0, w101 = wx1*wy0*wz1;
    const float w110 = wx1*wy1*wz0, w111 = wx1*wy1*wz1;

    float o0 = w000*f000.x;          float o1 = w000*f000.y;
    o0 = fmaf(w001, f001.x, o0);     o1 = fmaf(w001, f001.y, o1);
    o0 = fmaf(w010, f010.x, o0);     o1 = fmaf(w010, f010.y, o1);
    o0 = fmaf(w011, f011.x, o0);     o1 = fmaf(w011, f011.y, o1);
    o0 = fmaf(w100, f100.x, o0);     o1 = fmaf(w100, f100.y, o1);
    o0 = fmaf(w101, f101.x, o0);     o1 = fmaf(w101, f101.y, o1);
    o0 = fmaf(w110, f110.x, o0);     o1 = fmaf(w110, f110.y, o1);
    o0 = fmaf(w111, f111.x, o0);     o1 = fmaf(w111, f111.y, o1);

    featws[(size_t)l * NPTS + i] = make_float2(o0, o1);
}

// ---------------------------------------------------------------------------
// Kernel 2: density MLP + SH + color MLP. One thread per point.
// ---------------------------------------------------------------------------
__global__ __launch_bounds__(256) void mlp_k(
    const float2* __restrict__ featws,
    const float* __restrict__ dirs,
    const float* __restrict__ dw1, const float* __restrict__ db1,
    const float* __restrict__ dw2, const float* __restrict__ db2,
    const float* __restrict__ cw1, const float* __restrict__ cb1,
    const float* __restrict__ cw2, const float* __restrict__ cb2,
    const float* __restrict__ cw3, const float* __restrict__ cb3,
    const float* __restrict__ cw4, const float* __restrict__ cb4,
    float* __restrict__ out)
{
    const int i = blockIdx.x * 256 + threadIdx.x;

    float feat[32];
    #pragma unroll
    for (int l = 0; l < NLVL; ++l) {
        const float2 f = featws[(size_t)l * NPTS + i];
        feat[2*l+0] = f.x;
        feat[2*l+1] = f.y;
    }

    // ---------------- density MLP: 32 -> 64 (relu) -> 16 ----------------
    float h[64];
    #pragma unroll
    for (int j = 0; j < 64; ++j) h[j] = db1[j];
    #pragma unroll
    for (int k = 0; k < 32; ++k) {
        const float a = feat[k];
        #pragma unroll
        for (int j = 0; j < 64; ++j) h[j] = fmaf(a, dw1[64*k+j], h[j]);
    }
    #pragma unroll
    for (int j = 0; j < 64; ++j) h[j] = fmaxf(h[j], 0.f);

    float dob[16];
    #pragma unroll
    for (int j = 0; j < 16; ++j) dob[j] = db2[j];
    #pragma unroll
    for (int k = 0; k < 64; ++k) {
        const float a = h[k];
        #pragma unroll
        for (int j = 0; j < 16; ++j) dob[j] = fmaf(a, dw2[16*k+j], dob[j]);
    }

    // ---------------- SH encode (deg 4) ----------------
    const float dxr = dirs[3*i+0], dyr = dirs[3*i+1], dzr = dirs[3*i+2];
    const float inv = 1.f / sqrtf(dxr*dxr + dyr*dyr + dzr*dzr);
    float x = dxr*inv, y = dyr*inv, z = dzr*inv;
    x = ((x + 1.f) * 0.5f) * 2.f - 1.f;
    y = ((y + 1.f) * 0.5f) * 2.f - 1.f;
    z = ((z + 1.f) * 0.5f) * 2.f - 1.f;
    const float xx = x*x, yy = y*y, zz = z*z;
    const float xy = x*y, yz = y*z, xz = x*z;

    float inp[32];
    inp[0]  = 0.28209479177387814f;
    inp[1]  = -0.48860251190291987f * y;
    inp[2]  =  0.48860251190291987f * z;
    inp[3]  = -0.48860251190291987f * x;
    inp[4]  =  1.0925484305920792f  * xy;
    inp[5]  = -1.0925484305920792f  * yz;
    inp[6]  =  0.94617469575756f * zz - 0.31539156525252f;
    inp[7]  = -1.0925484305920792f  * xz;
    inp[8]  =  0.5462742152960396f  * (xx - yy);
    inp[9]  =  0.5900435899266435f  * y * (-3.f*xx + yy);
    inp[10] =  2.890611442640554f   * xy * z;
    inp[11] =  0.4570457994644657f  * y * (1.f - 5.f*zz);
    inp[12] =  0.3731763325901154f  * z * (5.f*zz - 3.f);
    inp[13] =  0.4570457994644657f  * x * (1.f - 5.f*zz);
    inp[14] =  1.445305721320277f   * z * (xx - yy);
    inp[15] =  0.5900435899266435f  * x * (xx - 3.f*yy);
    #pragma unroll
    for (int j = 0; j < 16; ++j) inp[16+j] = dob[j];

    // ---------------- color MLP: 32 -> 64 -> 64 -> 64 -> 3 ----------------
    float xa[64], xb[64];
    #pragma unroll
    for (int j = 0; j < 64; ++j) xa[j] = cb1[j];
    #pragma unroll
    for (int k = 0; k < 32; ++k) {
        const float a = inp[k];
        #pragma unroll
        for (int j = 0; j < 64; ++j) xa[j] = fmaf(a, cw1[64*k+j], xa[j]);
    }
    #pragma unroll
    for (int j = 0; j < 64; ++j) xa[j] = fmaxf(xa[j], 0.f);

    #pragma unroll
    for (int j = 0; j < 64; ++j) xb[j] = cb2[j];
    #pragma unroll
    for (int k = 0; k < 64; ++k) {
        const float a = xa[k];
        #pragma unroll
        for (int j = 0; j < 64; ++j) xb[j] = fmaf(a, cw2[64*k+j], xb[j]);
    }
    #pragma unroll
    for (int j = 0; j < 64; ++j) xb[j] = fmaxf(xb[j], 0.f);

    #pragma unroll
    for (int j = 0; j < 64; ++j) xa[j] = cb3[j];
    #pragma unroll
    for (int k = 0; k < 64; ++k) {
        const float a = xb[k];
        #pragma unroll
        for (int j = 0; j < 64; ++j) xa[j] = fmaf(a, cw3[64*k+j], xa[j]);
    }
    #pragma unroll
    for (int j = 0; j < 64; ++j) xa[j] = fmaxf(xa[j], 0.f);

    float c0 = cb4[0], c1 = cb4[1], c2 = cb4[2];
    #pragma unroll
    for (int k = 0; k < 64; ++k) {
        const float a = xa[k];
        c0 = fmaf(a, cw4[3*k+0], c0);
        c1 = fmaf(a, cw4[3*k+1], c1);
        c2 = fmaf(a, cw4[3*k+2], c2);
    }

    out[i] = expf(dob[0]);
    out[NPTS + 3*i + 0] = 1.f / (1.f + expf(-c0));
    out[NPTS + 3*i + 1] = 1.f / (1.f + expf(-c1));
    out[NPTS + 3*i + 2] = 1.f / (1.f + expf(-c2));
}

extern "C" void kernel_launch(void* const* d_in, const int* in_sizes, int n_in,
                              void* d_out, int out_size, void* d_ws, size_t ws_size,
                              hipStream_t stream)
{
    // RES must bit-match numpy: floor(16 * b**l) in f64, b = exp((ln512-ln16)/15).
    ResArr res;
    const double b = exp((log(512.0) - log(16.0)) / 15.0);
    for (int l = 0; l < NLVL; ++l)
        res.r[l] = (float)floor(16.0 * pow(b, (double)l));

    float2* featws = (float2*)d_ws;  // 16 * 262144 * 8 B = 33.5 MB

    dim3 g1(NPTS/256, NLVL);
    hash_encode_k<<<g1, 256, 0, stream>>>(
        (const float*)d_in[0],   // coords
        (const float*)d_in[2],   // embeddings
        featws, res);

    mlp_k<<<NPTS/256, 256, 0, stream>>>(
        featws,
        (const float*)d_in[1],   // directions
        (const float*)d_in[3],  (const float*)d_in[4],   // dw1, db1
        (const float*)d_in[5],  (const float*)d_in[6],   // dw2, db2
        (const float*)d_in[7],  (const float*)d_in[8],   // cw1, cb1
        (const float*)d_in[9],  (const float*)d_in[10],  // cw2, cb2
        (const float*)d_in[11], (const float*)d_in[12],  // cw3, cb3
        (const float*)d_in[13], (const float*)d_in[14],  // cw4, cb4
        (float*)d_out);
}

// Round 3
// 392.039 us; speedup vs baseline: 1.5164x; 1.5164x over previous
//
#include <hip/hip_runtime.h>
#include <cmath>

#define NPTS 262144
#define NLVL 16
#define TBL  524288u
#define TMASK 524287u
#define TPB  128   // points per block

typedef __attribute__((ext_vector_type(8))) short short8;
typedef __attribute__((ext_vector_type(4))) float f32x4;

struct ResArr { float r[NLVL]; };

__device__ __forceinline__ unsigned short f2bf(float f) {
    union { float f; unsigned u; } v; v.f = f;
    unsigned r = v.u + 0x7FFFu + ((v.u >> 16) & 1u);   // RNE
    return (unsigned short)(r >> 16);
}

#define MFMA(a,b,c) __builtin_amdgcn_mfma_f32_16x16x32_bf16((a),(b),(c),0,0,0)

__global__ __launch_bounds__(256, 3) void nerf_fused_mfma(
    const float* __restrict__ coords,
    const float* __restrict__ dirs,
    const float* __restrict__ emb,
    const float* __restrict__ dw1, const float* __restrict__ db1,
    const float* __restrict__ dw2, const float* __restrict__ db2,
    const float* __restrict__ cw1, const float* __restrict__ cb1,
    const float* __restrict__ cw2, const float* __restrict__ cb2,
    const float* __restrict__ cw3, const float* __restrict__ cb3,
    const float* __restrict__ cw4, const float* __restrict__ cb4,
    float* __restrict__ out, ResArr res)
{
    const int tid  = threadIdx.x;
    const int wid  = tid >> 6;
    const int lane = tid & 63;
    const int m16  = lane & 15;
    const int q    = lane >> 4;

    // 28 MFMA B-fragment sets (16x16x32): 1024 B each
    __shared__ __align__(16) unsigned short wlds[28 * 512];
    __shared__ float blds[288];
    __shared__ float resL[NLVL];
    __shared__ __align__(16) unsigned short featL[TPB * 40];   // [point][32 feats + 8 pad] bf16
    __shared__ __align__(16) unsigned short actL[4 * 16 * 72]; // per-wave [16 rows][64 + 8 pad] bf16

    // ---------------- stage weight B-fragments (bf16) ----------------
    // set s -> (matrix, k0, n0); B-frag layout: lane holds B[k0+q*8+j][n0+(lane&15)], j=0..7
    const unsigned char MAT[28] = {0,0,0,0, 1,1, 2,2,2,2, 3,3,3,3,3,3,3,3, 4,4,4,4,4,4,4,4, 5,5};
    const unsigned char K0 [28] = {0,0,0,0, 0,32, 0,0,0,0, 0,0,0,0,32,32,32,32, 0,0,0,0,32,32,32,32, 0,32};
    const unsigned char N0 [28] = {0,16,32,48, 0,0, 0,16,32,48, 0,16,32,48,0,16,32,48, 0,16,32,48,0,16,32,48, 0,0};

    #pragma unroll
    for (int s = 0; s < 28; ++s) {
        if ((s & 3) == wid) {
            const int mat = MAT[s];
            const float* src = mat==0?dw1 : mat==1?dw2 : mat==2?cw1 : mat==3?cw2 : mat==4?cw3 : cw4;
            const int fan = (mat==1) ? 16 : (mat==5) ? 3 : 64;
            const int k = (int)K0[s] + q*8;
            const int n = (int)N0[s] + m16;
            unsigned short u[8];
            #pragma unroll
            for (int j = 0; j < 8; ++j) {
                float v = 0.f;
                if (mat != 5 || n < 3) v = src[(k+j)*fan + n];
                u[j] = f2bf(v);
            }
            unsigned* w32 = (unsigned*)(wlds + s*512 + lane*8);
            w32[0] = (unsigned)u[0] | ((unsigned)u[1] << 16);
            w32[1] = (unsigned)u[2] | ((unsigned)u[3] << 16);
            w32[2] = (unsigned)u[4] | ((unsigned)u[5] << 16);
            w32[3] = (unsigned)u[6] | ((unsigned)u[7] << 16);
        }
    }
    // biases: [0,64)=db1 [64,80)=db2 [80,144)=cb1 [144,208)=cb2 [208,272)=cb3 [272,288)=cb4(pad0)
    {
        int t = tid;
        if      (t <  64) blds[t] = db1[t];
        else if (t <  80) blds[t] = db2[t-64];
        else if (t < 144) blds[t] = cb1[t-80];
        else if (t < 208) blds[t] = cb2[t-144];
    }
    if (tid < 80) {
        int t = tid + 208;
        if (t < 272) blds[t] = cb3[t-208];
        else         blds[t] = (t-272 < 3) ? cb4[t-272] : 0.f;
    }
    if (tid == 0) {
        #pragma unroll
        for (int j = 0; j < NLVL; ++j) resL[j] = res.r[j];
    }
    __syncthreads();

    // ---------------- hash-grid gather: thread = (point, level-pair) ----------------
    // 16 independent gathers in flight per thread per pass
    const int pbase = blockIdx.x * TPB;
    const float2* __restrict__ emb2 = (const float2*)emb;

    #pragma unroll
    for (int pass = 0; pass < 4; ++pass) {
        const int ploc = pass*32 + (lane & 31);
        const int lp   = wid*2 + (lane >> 5);      // 0..7 -> levels lp, lp+8
        const int p    = pbase + ploc;
        const float cx = coords[3*p], cy = coords[3*p+1], cz = coords[3*p+2];

        unsigned idxs[16];
        float    wgt[16];
        #pragma unroll
        for (int t2 = 0; t2 < 2; ++t2) {
            const int l = lp + t2*8;
            const float r = resL[l];
            const float px = cx*r, py = cy*r, pz = cz*r;
            const float fpx = floorf(px), fpy = floorf(py), fpz = floorf(pz);
            const float fx = px-fpx, fy = py-fpy, fz = pz-fpz;
            const unsigned ix=(unsigned)fpx, iy=(unsigned)fpy, iz=(unsigned)fpz;
            const unsigned hx0=ix,                hx1=ix+1u;
            const unsigned hy0=iy*2654435761u,    hy1=(iy+1u)*2654435761u;
            const unsigned hz0=iz*805459861u,     hz1=(iz+1u)*805459861u;
            const unsigned base = (unsigned)l * TBL;
            idxs[t2*8+0] = base + ((hx0^hy0^hz0)&TMASK);
            idxs[t2*8+1] = base + ((hx0^hy0^hz1)&TMASK);
            idxs[t2*8+2] = base + ((hx0^hy1^hz0)&TMASK);
            idxs[t2*8+3] = base + ((hx0^hy1^hz1)&TMASK);
            idxs[t2*8+4] = base + ((hx1^hy0^hz0)&TMASK);
            idxs[t2*8+5] = base + ((hx1^hy0^hz1)&TMASK);
            idxs[t2*8+6] = base + ((hx1^hy1^hz0)&TMASK);
            idxs[t2*8+7] = base + ((hx1^hy1^hz1)&TMASK);
            const float wx0=1.f-fx, wy0=1.f-fy, wz0=1.f-fz;
            wgt[t2*8+0]=wx0*wy0*wz0; wgt[t2*8+1]=wx0*wy0*fz;
            wgt[t2*8+2]=wx0*fy*wz0;  wgt[t2*8+3]=wx0*fy*fz;
            wgt[t2*8+4]=fx*wy0*wz0;  wgt[t2*8+5]=fx*wy0*fz;
            wgt[t2*8+6]=fx*fy*wz0;   wgt[t2*8+7]=fx*fy*fz;
        }
        float2 f[16];
        #pragma unroll
        for (int j = 0; j < 16; ++j) f[j] = emb2[idxs[j]];
        #pragma unroll
        for (int t2 = 0; t2 < 2; ++t2) {
            float o0 = 0.f, o1 = 0.f;
            #pragma unroll
            for (int c = 0; c < 8; ++c) {
                o0 = fmaf(wgt[t2*8+c], f[t2*8+c].x, o0);
                o1 = fmaf(wgt[t2*8+c], f[t2*8+c].y, o1);
            }
            const int l = lp + t2*8;
            *(unsigned*)(featL + ploc*40 + l*2) =
                (unsigned)f2bf(o0) | ((unsigned)f2bf(o1) << 16);
        }
    }
    __syncthreads();

    // ---------------- MFMA MLP chain: wave handles tiles (wid, wid+4) ----------------
    unsigned short* aw = actL + wid*1152;  // 16 x 72
    const short8* wfr = (const short8*)wlds;   // B(s) = wfr[s*64 + lane]

    #pragma unroll
    for (int iter = 0; iter < 2; ++iter) {
        const int tile = wid + 4*iter;
        const int loc0 = tile*16;
        const int p0g  = pbase + loc0;

        // ---- density L1: feat(32) -> 64, relu ----
        short8 a0 = *(const short8*)(featL + (loc0+m16)*40 + q*8);
        f32x4 acc[4];
        #pragma unroll
        for (int nc = 0; nc < 4; ++nc) {
            const float b = blds[nc*16 + m16];
            acc[nc] = (f32x4){b,b,b,b};
            acc[nc] = MFMA(a0, wfr[nc*64 + lane], acc[nc]);
        }
        #pragma unroll
        for (int nc = 0; nc < 4; ++nc)
            #pragma unroll
            for (int r = 0; r < 4; ++r)
                aw[(q*4+r)*72 + nc*16 + m16] = f2bf(fmaxf(acc[nc][r], 0.f));

        // ---- density L2: 64 -> 16 (no act) ----
        short8 ad0 = *(const short8*)(aw + m16*72 + q*8);
        short8 ad1 = *(const short8*)(aw + m16*72 + 32 + q*8);
        f32x4 dob;
        { const float b = blds[64 + m16]; dob = (f32x4){b,b,b,b}; }
        dob = MFMA(ad0, wfr[4*64 + lane], dob);
        dob = MFMA(ad1, wfr[5*64 + lane], dob);

        // density output = exp(dob[:,0])
        if (m16 == 0) {
            #pragma unroll
            for (int r = 0; r < 4; ++r) out[p0g + q*4 + r] = expf(dob[r]);
        }

        // ---- build inp = [SH(16) | dob(16)] in aw ----
        #pragma unroll
        for (int r = 0; r < 4; ++r)
            aw[(q*4+r)*72 + 16 + m16] = f2bf(dob[r]);
        {
            const int pg = p0g + m16;
            const float dx0 = dirs[3*pg], dy0 = dirs[3*pg+1], dz0 = dirs[3*pg+2];
            const float inv = 1.f / sqrtf(dx0*dx0 + dy0*dy0 + dz0*dz0);
            float x = dx0*inv, y = dy0*inv, z = dz0*inv;
            x = ((x+1.f)*0.5f)*2.f - 1.f;
            y = ((y+1.f)*0.5f)*2.f - 1.f;
            z = ((z+1.f)*0.5f)*2.f - 1.f;
            float s0, s1, s2, s3;
            switch (q) {
            case 0: s0 = 0.28209479177387814f;
                    s1 = -0.48860251190291987f*y;
                    s2 =  0.48860251190291987f*z;
                    s3 = -0.48860251190291987f*x; break;
            case 1: s0 =  1.0925484305920792f*x*y;
                    s1 = -1.0925484305920792f*y*z;
                    s2 =  0.94617469575756f*z*z - 0.31539156525252f;
                    s3 = -1.0925484305920792f*x*z; break;
            case 2: s0 =  0.5462742152960396f*(x*x - y*y);
                    s1 =  0.5900435899266435f*y*(-3.f*x*x + y*y);
                    s2 =  2.890611442640554f*x*y*z;
                    s3 =  0.4570457994644657f*y*(1.f - 5.f*z*z); break;
            default:s0 =  0.3731763325901154f*z*(5.f*z*z - 3.f);
                    s1 =  0.4570457994644657f*x*(1.f - 5.f*z*z);
                    s2 =  1.445305721320277f*z*(x*x - y*y);
                    s3 =  0.5900435899266435f*x*(x*x - 3.f*y*y); break;
            }
            unsigned* ip = (unsigned*)(aw + m16*72 + q*4);
            ip[0] = (unsigned)f2bf(s0) | ((unsigned)f2bf(s1) << 16);
            ip[1] = (unsigned)f2bf(s2) | ((unsigned)f2bf(s3) << 16);
        }

        // ---- color L1: inp(32) -> 64, relu ----
        short8 ac0 = *(const short8*)(aw + m16*72 + q*8);
        #pragma unroll
        for (int nc = 0; nc < 4; ++nc) {
            const float b = blds[80 + nc*16 + m16];
            acc[nc] = (f32x4){b,b,b,b};
            acc[nc] = MFMA(ac0, wfr[(6+nc)*64 + lane], acc[nc]);
        }
        #pragma unroll
        for (int nc = 0; nc < 4; ++nc)
            #pragma unroll
            for (int r = 0; r < 4; ++r)
                aw[(q*4+r)*72 + nc*16 + m16] = f2bf(fmaxf(acc[nc][r], 0.f));

        // ---- color L2: 64 -> 64, relu ----
        short8 a20 = *(const short8*)(aw + m16*72 + q*8);
        short8 a21 = *(const short8*)(aw + m16*72 + 32 + q*8);
        #pragma unroll
        for (int nc = 0; nc < 4; ++nc) {
            const float b = blds[144 + nc*16 + m16];
            acc[nc] = (f32x4){b,b,b,b};
            acc[nc] = MFMA(a20, wfr[(10+nc)*64 + lane], acc[nc]);
            acc[nc] = MFMA(a21, wfr[(14+nc)*64 + lane], acc[nc]);
        }
        #pragma unroll
        for (int nc = 0; nc < 4; ++nc)
            #pragma unroll
            for (int r = 0; r < 4; ++r)
                aw[(q*4+r)*72 + nc*16 + m16] = f2bf(fmaxf(acc[nc][r], 0.f));

        // ---- color L3: 64 -> 64, relu ----
        short8 a30 = *(const short8*)(aw + m16*72 + q*8);
        short8 a31 = *(const short8*)(aw + m16*72 + 32 + q*8);
        #pragma unroll
        for (int nc = 0; nc < 4; ++nc) {
            const float b = blds[208 + nc*16 + m16];
            acc[nc] = (f32x4){b,b,b,b};
            acc[nc] = MFMA(a30, wfr[(18+nc)*64 + lane], acc[nc]);
            acc[nc] = MFMA(a31, wfr[(22+nc)*64 + lane], acc[nc]);
        }
        #pragma unroll
        for (int nc = 0; nc < 4; ++nc)
            #pragma unroll
            for (int r = 0; r < 4; ++r)
                aw[(q*4+r)*72 + nc*16 + m16] = f2bf(fmaxf(acc[nc][r], 0.f));

        // ---- color L4: 64 -> 3 (padded to 16), sigmoid ----
        short8 a40 = *(const short8*)(aw + m16*72 + q*8);
        short8 a41 = *(const short8*)(aw + m16*72 + 32 + q*8);
        f32x4 c4;
        { const float b = blds[272 + m16]; c4 = (f32x4){b,b,b,b}; }
        c4 = MFMA(a40, wfr[26*64 + lane], c4);
        c4 = MFMA(a41, wfr[27*64 + lane], c4);
        if (m16 < 3) {
            #pragma unroll
            for (int r = 0; r < 4; ++r)
                out[NPTS + 3*(p0g + q*4 + r) + m16] = 1.f / (1.f + expf(-c4[r]));
        }
    }
}

extern "C" void kernel_launch(void* const* d_in, const int* in_sizes, int n_in,
                              void* d_out, int out_size, void* d_ws, size_t ws_size,
                              hipStream_t stream)
{
    // RES must bit-match numpy: floor(16 * b**l) in f64, b = exp((ln512-ln16)/15).
    ResArr res;
    const double b = exp((log(512.0) - log(16.0)) / 15.0);
    for (int l = 0; l < NLVL; ++l)
        res.r[l] = (float)floor(16.0 * pow(b, (double)l));

    nerf_fused_mfma<<<NPTS/TPB, 256, 0, stream>>>(
        (const float*)d_in[0],   // coords
        (const float*)d_in[1],   // directions
        (const float*)d_in[2],   // embeddings
        (const float*)d_in[3],  (const float*)d_in[4],   // dw1, db1
        (const float*)d_in[5],  (const float*)d_in[6],   // dw2, db2
        (const float*)d_in[7],  (const float*)d_in[8],   // cw1, cb1
        (const float*)d_in[9],  (const float*)d_in[10],  // cw2, cb2
        (const float*)d_in[11], (const float*)d_in[12],  // cw3, cb3
        (const float*)d_in[13], (const float*)d_in[14],  // cw4, cb4
        (float*)d_out, res);
}

// Round 4
// 270.140 us; speedup vs baseline: 2.2007x; 1.4512x over previous
//
#include <hip/hip_runtime.h>
#include <cmath>

#define NPTS 262144
#define NLVL 16
#define TBL  524288u
#define TMASK 524287u
#define TPB  128   // points per block (k2)

typedef __attribute__((ext_vector_type(8))) short short8;
typedef __attribute__((ext_vector_type(4))) float f32x4;

struct ResArr { float r[NLVL]; };

__device__ __forceinline__ unsigned short f2bf(float f) {
    union { float f; unsigned u; } v; v.f = f;
    unsigned r = v.u + 0x7FFFu + ((v.u >> 16) & 1u);   // RNE
    return (unsigned short)(r >> 16);
}

#define MFMA(a,b,c) __builtin_amdgcn_mfma_f32_16x16x32_bf16((a),(b),(c),0,0,0)

// ---------------------------------------------------------------------------
// Kernel 1: hash-grid encode, XCD-pinned by level.
// block b -> XCD (b&7); level = (b&7) for first half of steps, (b&7)+8 after.
// Each XCD streams ONE ~4MB level slab at a time -> L2-resident.
// Writes featws[level][pt] as packed bf16 pair (coalesced 4B stores).
// ---------------------------------------------------------------------------
__global__ __launch_bounds__(256) void hash_encode_k(
    const float* __restrict__ coords,
    const float* __restrict__ emb,
    unsigned* __restrict__ featws,
    ResArr res)
{
    const int b    = blockIdx.x;
    const int xcd  = b & 7;
    const int step = b >> 3;                    // 0..2047
    const int l    = (step < 1024) ? xcd : (xcd + 8);
    const int p    = (step & 1023) * 256 + threadIdx.x;

    const float cx = coords[3*p], cy = coords[3*p+1], cz = coords[3*p+2];
    const float r = res.r[l];

    const float px = cx*r, py = cy*r, pz = cz*r;
    const float fpx = floorf(px), fpy = floorf(py), fpz = floorf(pz);
    const float fx = px-fpx, fy = py-fpy, fz = pz-fpz;
    const unsigned ix=(unsigned)fpx, iy=(unsigned)fpy, iz=(unsigned)fpz;
    const unsigned hx0=ix,             hx1=ix+1u;
    const unsigned hy0=iy*2654435761u, hy1=(iy+1u)*2654435761u;
    const unsigned hz0=iz*805459861u,  hz1=(iz+1u)*805459861u;
    const unsigned base = (unsigned)l * TBL;

    const float2* __restrict__ emb2 = (const float2*)emb;
    const float2 f000 = emb2[base + ((hx0^hy0^hz0)&TMASK)];
    const float2 f001 = emb2[base + ((hx0^hy0^hz1)&TMASK)];
    const float2 f010 = emb2[base + ((hx0^hy1^hz0)&TMASK)];
    const float2 f011 = emb2[base + ((hx0^hy1^hz1)&TMASK)];
    const float2 f100 = emb2[base + ((hx1^hy0^hz0)&TMASK)];
    const float2 f101 = emb2[base + ((hx1^hy0^hz1)&TMASK)];
    const float2 f110 = emb2[base + ((hx1^hy1^hz0)&TMASK)];
    const float2 f111 = emb2[base + ((hx1^hy1^hz1)&TMASK)];

    const float wx0=1.f-fx, wy0=1.f-fy, wz0=1.f-fz;
    float o0, o1;
    o0 = wx0*wy0*wz0*f000.x;                 o1 = wx0*wy0*wz0*f000.y;
    o0 = fmaf(wx0*wy0*fz,  f001.x, o0);      o1 = fmaf(wx0*wy0*fz,  f001.y, o1);
    o0 = fmaf(wx0*fy*wz0,  f010.x, o0);      o1 = fmaf(wx0*fy*wz0,  f010.y, o1);
    o0 = fmaf(wx0*fy*fz,   f011.x, o0);      o1 = fmaf(wx0*fy*fz,   f011.y, o1);
    o0 = fmaf(fx*wy0*wz0,  f100.x, o0);      o1 = fmaf(fx*wy0*wz0,  f100.y, o1);
    o0 = fmaf(fx*wy0*fz,   f101.x, o0);      o1 = fmaf(fx*wy0*fz,   f101.y, o1);
    o0 = fmaf(fx*fy*wz0,   f110.x, o0);      o1 = fmaf(fx*fy*wz0,   f110.y, o1);
    o0 = fmaf(fx*fy*fz,    f111.x, o0);      o1 = fmaf(fx*fy*fz,    f111.y, o1);

    featws[(size_t)l * NPTS + p] = (unsigned)f2bf(o0) | ((unsigned)f2bf(o1) << 16);
}

// ---------------------------------------------------------------------------
// Kernel 2: MFMA MLP chain (density + SH + color). 128 points/block.
// ---------------------------------------------------------------------------
__global__ __launch_bounds__(256, 3) void mlp_mfma_k(
    const unsigned* __restrict__ featws,
    const float* __restrict__ dirs,
    const float* __restrict__ dw1, const float* __restrict__ db1,
    const float* __restrict__ dw2, const float* __restrict__ db2,
    const float* __restrict__ cw1, const float* __restrict__ cb1,
    const float* __restrict__ cw2, const float* __restrict__ cb2,
    const float* __restrict__ cw3, const float* __restrict__ cb3,
    const float* __restrict__ cw4, const float* __restrict__ cb4,
    float* __restrict__ out)
{
    const int tid  = threadIdx.x;
    const int wid  = tid >> 6;
    const int lane = tid & 63;
    const int m16  = lane & 15;
    const int q    = lane >> 4;

    __shared__ __align__(16) unsigned short wlds[28 * 512];
    __shared__ float blds[288];
    __shared__ __align__(16) unsigned short featL[TPB * 40];   // [pt][32 feats + 8 pad] bf16
    __shared__ __align__(16) unsigned short actL[4 * 16 * 72]; // per-wave [16][64+8 pad] bf16

    // ---------------- stage weight B-fragments (bf16) ----------------
    const unsigned char MAT[28] = {0,0,0,0, 1,1, 2,2,2,2, 3,3,3,3,3,3,3,3, 4,4,4,4,4,4,4,4, 5,5};
    const unsigned char K0 [28] = {0,0,0,0, 0,32, 0,0,0,0, 0,0,0,0,32,32,32,32, 0,0,0,0,32,32,32,32, 0,32};
    const unsigned char N0 [28] = {0,16,32,48, 0,0, 0,16,32,48, 0,16,32,48,0,16,32,48, 0,16,32,48,0,16,32,48, 0,0};

    #pragma unroll
    for (int s = 0; s < 28; ++s) {
        if ((s & 3) == wid) {
            const int mat = MAT[s];
            const float* src = mat==0?dw1 : mat==1?dw2 : mat==2?cw1 : mat==3?cw2 : mat==4?cw3 : cw4;
            const int fan = (mat==1) ? 16 : (mat==5) ? 3 : 64;
            const int k = (int)K0[s] + q*8;
            const int n = (int)N0[s] + m16;
            unsigned short u[8];
            #pragma unroll
            for (int j = 0; j < 8; ++j) {
                float v = 0.f;
                if (mat != 5 || n < 3) v = src[(k+j)*fan + n];
                u[j] = f2bf(v);
            }
            unsigned* w32 = (unsigned*)(wlds + s*512 + lane*8);
            w32[0] = (unsigned)u[0] | ((unsigned)u[1] << 16);
            w32[1] = (unsigned)u[2] | ((unsigned)u[3] << 16);
            w32[2] = (unsigned)u[4] | ((unsigned)u[5] << 16);
            w32[3] = (unsigned)u[6] | ((unsigned)u[7] << 16);
        }
    }
    // biases
    {
        int t = tid;
        if      (t <  64) blds[t] = db1[t];
        else if (t <  80) blds[t] = db2[t-64];
        else if (t < 144) blds[t] = cb1[t-80];
        else if (t < 208) blds[t] = cb2[t-144];
    }
    if (tid < 80) {
        int t = tid + 208;
        if (t < 272) blds[t] = cb3[t-208];
        else         blds[t] = (t-272 < 3) ? cb4[t-272] : 0.f;
    }

    // ---------------- stage feats from global (coalesced) ----------------
    const int pbase = blockIdx.x * TPB;
    unsigned* fL32 = (unsigned*)featL;        // row stride 20 uints
    #pragma unroll
    for (int j = 0; j < 8; ++j) {
        const int idx  = j*256 + tid;         // 0..2047
        const int l    = idx >> 7;
        const int ploc = idx & 127;
        fL32[ploc*20 + l] = featws[(size_t)l * NPTS + pbase + ploc];
    }
    __syncthreads();

    // ---------------- MFMA MLP chain: wave handles tiles (wid, wid+4) ----------------
    unsigned short* aw = actL + wid*1152;     // 16 x 72
    const short8* wfr = (const short8*)wlds;  // B(s) = wfr[s*64 + lane]

    #pragma unroll
    for (int iter = 0; iter < 2; ++iter) {
        const int tile = wid + 4*iter;
        const int loc0 = tile*16;
        const int p0g  = pbase + loc0;

        // ---- density L1: feat(32) -> 64, relu ----
        short8 a0 = *(const short8*)(featL + (loc0+m16)*40 + q*8);
        f32x4 acc[4];
        #pragma unroll
        for (int nc = 0; nc < 4; ++nc) {
            const float b = blds[nc*16 + m16];
            acc[nc] = (f32x4){b,b,b,b};
            acc[nc] = MFMA(a0, wfr[nc*64 + lane], acc[nc]);
        }
        #pragma unroll
        for (int nc = 0; nc < 4; ++nc)
            #pragma unroll
            for (int r = 0; r < 4; ++r)
                aw[(q*4+r)*72 + nc*16 + m16] = f2bf(fmaxf(acc[nc][r], 0.f));

        // ---- density L2: 64 -> 16 (no act) ----
        short8 ad0 = *(const short8*)(aw + m16*72 + q*8);
        short8 ad1 = *(const short8*)(aw + m16*72 + 32 + q*8);
        f32x4 dob;
        { const float b = blds[64 + m16]; dob = (f32x4){b,b,b,b}; }
        dob = MFMA(ad0, wfr[4*64 + lane], dob);
        dob = MFMA(ad1, wfr[5*64 + lane], dob);

        if (m16 == 0) {
            #pragma unroll
            for (int r = 0; r < 4; ++r) out[p0g + q*4 + r] = expf(dob[r]);
        }

        // ---- build inp = [SH(16) | dob(16)] in aw ----
        #pragma unroll
        for (int r = 0; r < 4; ++r)
            aw[(q*4+r)*72 + 16 + m16] = f2bf(dob[r]);
        {
            const int pg = p0g + m16;
            const float dx0 = dirs[3*pg], dy0 = dirs[3*pg+1], dz0 = dirs[3*pg+2];
            const float inv = 1.f / sqrtf(dx0*dx0 + dy0*dy0 + dz0*dz0);
            float x = dx0*inv, y = dy0*inv, z = dz0*inv;
            x = ((x+1.f)*0.5f)*2.f - 1.f;
            y = ((y+1.f)*0.5f)*2.f - 1.f;
            z = ((z+1.f)*0.5f)*2.f - 1.f;
            float s0, s1, s2, s3;
            switch (q) {
            case 0: s0 = 0.28209479177387814f;
                    s1 = -0.48860251190291987f*y;
                    s2 =  0.48860251190291987f*z;
                    s3 = -0.48860251190291987f*x; break;
            case 1: s0 =  1.0925484305920792f*x*y;
                    s1 = -1.0925484305920792f*y*z;
                    s2 =  0.94617469575756f*z*z - 0.31539156525252f;
                    s3 = -1.0925484305920792f*x*z; break;
            case 2: s0 =  0.5462742152960396f*(x*x - y*y);
                    s1 =  0.5900435899266435f*y*(-3.f*x*x + y*y);
                    s2 =  2.890611442640554f*x*y*z;
                    s3 =  0.4570457994644657f*y*(1.f - 5.f*z*z); break;
            default:s0 =  0.3731763325901154f*z*(5.f*z*z - 3.f);
                    s1 =  0.4570457994644657f*x*(1.f - 5.f*z*z);
                    s2 =  1.445305721320277f*z*(x*x - y*y);
                    s3 =  0.5900435899266435f*x*(x*x - 3.f*y*y); break;
            }
            unsigned* ip = (unsigned*)(aw + m16*72 + q*4);
            ip[0] = (unsigned)f2bf(s0) | ((unsigned)f2bf(s1) << 16);
            ip[1] = (unsigned)f2bf(s2) | ((unsigned)f2bf(s3) << 16);
        }

        // ---- color L1: inp(32) -> 64, relu ----
        short8 ac0 = *(const short8*)(aw + m16*72 + q*8);
        #pragma unroll
        for (int nc = 0; nc < 4; ++nc) {
            const float b = blds[80 + nc*16 + m16];
            acc[nc] = (f32x4){b,b,b,b};
            acc[nc] = MFMA(ac0, wfr[(6+nc)*64 + lane], acc[nc]);
        }
        #pragma unroll
        for (int nc = 0; nc < 4; ++nc)
            #pragma unroll
            for (int r = 0; r < 4; ++r)
                aw[(q*4+r)*72 + nc*16 + m16] = f2bf(fmaxf(acc[nc][r], 0.f));

        // ---- color L2: 64 -> 64, relu ----
        short8 a20 = *(const short8*)(aw + m16*72 + q*8);
        short8 a21 = *(const short8*)(aw + m16*72 + 32 + q*8);
        #pragma unroll
        for (int nc = 0; nc < 4; ++nc) {
            const float b = blds[144 + nc*16 + m16];
            acc[nc] = (f32x4){b,b,b,b};
            acc[nc] = MFMA(a20, wfr[(10+nc)*64 + lane], acc[nc]);
            acc[nc] = MFMA(a21, wfr[(14+nc)*64 + lane], acc[nc]);
        }
        #pragma unroll
        for (int nc = 0; nc < 4; ++nc)
            #pragma unroll
            for (int r = 0; r < 4; ++r)
                aw[(q*4+r)*72 + nc*16 + m16] = f2bf(fmaxf(acc[nc][r], 0.f));

        // ---- color L3: 64 -> 64, relu ----
        short8 a30 = *(const short8*)(aw + m16*72 + q*8);
        short8 a31 = *(const short8*)(aw + m16*72 + 32 + q*8);
        #pragma unroll
        for (int nc = 0; nc < 4; ++nc) {
            const float b = blds[208 + nc*16 + m16];
            acc[nc] = (f32x4){b,b,b,b};
            acc[nc] = MFMA(a30, wfr[(18+nc)*64 + lane], acc[nc]);
            acc[nc] = MFMA(a31, wfr[(22+nc)*64 + lane], acc[nc]);
        }
        #pragma unroll
        for (int nc = 0; nc < 4; ++nc)
            #pragma unroll
            for (int r = 0; r < 4; ++r)
                aw[(q*4+r)*72 + nc*16 + m16] = f2bf(fmaxf(acc[nc][r], 0.f));

        // ---- color L4: 64 -> 3 (padded to 16), sigmoid ----
        short8 a40 = *(const short8*)(aw + m16*72 + q*8);
        short8 a41 = *(const short8*)(aw + m16*72 + 32 + q*8);
        f32x4 c4;
        { const float b = blds[272 + m16]; c4 = (f32x4){b,b,b,b}; }
        c4 = MFMA(a40, wfr[26*64 + lane], c4);
        c4 = MFMA(a41, wfr[27*64 + lane], c4);
        if (m16 < 3) {
            #pragma unroll
            for (int r = 0; r < 4; ++r)
                out[NPTS + 3*(p0g + q*4 + r) + m16] = 1.f / (1.f + expf(-c4[r]));
        }
    }
}

extern "C" void kernel_launch(void* const* d_in, const int* in_sizes, int n_in,
                              void* d_out, int out_size, void* d_ws, size_t ws_size,
                              hipStream_t stream)
{
    // RES must bit-match numpy: floor(16 * b**l) in f64, b = exp((ln512-ln16)/15).
    ResArr res;
    const double b = exp((log(512.0) - log(16.0)) / 15.0);
    for (int l = 0; l < NLVL; ++l)
        res.r[l] = (float)floor(16.0 * pow(b, (double)l));

    unsigned* featws = (unsigned*)d_ws;   // 16 * 262144 * 4 B = 16.8 MB

    hash_encode_k<<<16384, 256, 0, stream>>>(
        (const float*)d_in[0],   // coords
        (const float*)d_in[2],   // embeddings
        featws, res);

    mlp_mfma_k<<<NPTS/TPB, 256, 0, stream>>>(
        featws,
        (const float*)d_in[1],   // directions
        (const float*)d_in[3],  (const float*)d_in[4],   // dw1, db1
        (const float*)d_in[5],  (const float*)d_in[6],   // dw2, db2
        (const float*)d_in[7],  (const float*)d_in[8],   // cw1, cb1
        (const float*)d_in[9],  (const float*)d_in[10],  // cw2, cb2
        (const float*)d_in[11], (const float*)d_in[12],  // cw3, cb3
        (const float*)d_in[13], (const float*)d_in[14],  // cw4, cb4
        (float*)d_out);
}